// Round 9
// baseline (1050.880 us; speedup 1.0000x reference)
//
#include <hip/hip_runtime.h>

// SlotAttention, algebraically restructured:
//   logits = (LN(slots) @ (Wq^T @ Wk)) . x / 16   (q.bk term dropped: softmax-invariant)
//   updates = softmax-weighted-avg(x) @ Wv^T + bv  (attn rows sum to 1)
// R5-R12 history: six attn structures (bf16 x5, fp8 x1) all ~680 us timed. fp8
//   halving of attn bytes saved only ~21 us -> attn is byte-INDEPENDENT-bound:
//   per-block phase pipeline (13 barriers, serial A->B chains) + latency.
// R13: two shallow kernels instead of one deep pipeline:
//   kA: 4096 blocks, NO LDS, NO barriers. One 16-row tile per wave: 8 chained
//       fp8 MFMAs with both operands from global (L3-resident), exp, P bytes to
//       global (2MB), l-sums via atomicAdd. it0 converts fp32->fp8 inline.
//   kB: 1024 blocks, transpose-only LDS (double-buffered, 1 barrier/chunk),
//       P fragments hoisted from global; U accumulated by atomicAdd into a
//       per-iter 0.5MB buffer -> pu (33.5MB) eliminated; upd combine collapses
//       to a single 0.5MB read. q stored fp8 by qk0/upd. pl/U zeroed in k_prep.

constexpr int Bn = 64;    // batch
constexpr int Nn = 4096;  // inputs per batch
constexpr int Dd = 256;   // feature dim (== IN_D)
constexpr int Ss = 8;     // slots
constexpr int CH = 16;    // N-chunks per batch (256-row units for kB)
constexpr float EPSF = 1e-5f;

#define DEV __device__ __forceinline__

using short8 = __attribute__((ext_vector_type(8))) short;
using f32x4 = __attribute__((ext_vector_type(4))) float;
union U8 { short8 s; uint4 u; };
union LL { unsigned u[2]; long long l; };

DEV unsigned bfpack2(float lo, float hi) {
  unsigned ul = __float_as_uint(lo), uh = __float_as_uint(hi);
  ul = (ul + 0x7FFFu + ((ul >> 16) & 1u)) >> 16;         // RNE to bf16
  uh = (uh + 0x7FFFu + ((uh >> 16) & 1u)) & 0xFFFF0000u;
  return ul | uh;
}
DEV unsigned short bf16r(float x) {
  unsigned u = __float_as_uint(x);
  u = (u + 0x7FFFu + ((u >> 16) & 1u)) >> 16;
  return (unsigned short)u;
}
// fp32 -> OCP e4m3fn, RNE, satfinite. bias 7, max 448, denorm step 2^-9.
DEV unsigned f8q(float x) {
  unsigned u = __float_as_uint(x), s = (u >> 24) & 0x80u;
  float a = __uint_as_float(u & 0x7FFFFFFFu);
  if (a >= 448.f) return s | 0x7Eu;
  if (a < 0.015625f) {
    int m = (int)rintf(a * 512.f);
    return s | (unsigned)m;
  }
  unsigned v = (u & 0x7FFFFFFFu) + 0x7FFFFu + ((u >> 20) & 1u);
  unsigned E = (v >> 23) - 120u;
  unsigned M = (v >> 20) & 7u;
  if (E > 15u) return s | 0x7Eu;
  unsigned r = (E << 3) | M;
  if (r > 0x7Eu) r = 0x7Eu;
  return s | r;
}
DEV float rsum32(float v) {  // sum within each 32-lane half of a wave
  v += __shfl_xor(v, 1); v += __shfl_xor(v, 2); v += __shfl_xor(v, 4);
  v += __shfl_xor(v, 8); v += __shfl_xor(v, 16);
  return v;
}
DEV float sigm(float x) { return 1.f / (1.f + __expf(-x)); }

// ---- bf16 MFMA tile helpers (k_upd/k_qk0 path) ----
template <int NK>
DEV void load_af(short8* a, const unsigned short* base, int lda, int m16, int quad) {
  const unsigned short* p = base + m16 * lda + quad * 8;
#pragma unroll
  for (int kk = 0; kk < NK; ++kk) a[kk] = *(const short8*)(p + kk * 32);
}
template <int NK>
DEV f32x4 gemm_tile(const short8* a, const unsigned short* wr, float binit) {
  f32x4 acc = {binit, binit, binit, binit};
#pragma unroll
  for (int kk = 0; kk < NK; ++kk) {
    short8 b = *(const short8*)(wr + kk * 32);
    acc = __builtin_amdgcn_mfma_f32_16x16x32_bf16(a[kk], b, acc, 0, 0, 0);
  }
  return acc;
}

// LayerNorm over one 256-row held 8-per-thread by 32 lanes; writes bf16 packed out.
DEV void ln_row8(const float* x, const float* g, const float* b, int d0,
                 unsigned short* dst) {
  float s = x[0] + x[1] + x[2] + x[3] + x[4] + x[5] + x[6] + x[7];
  float mu = rsum32(s) * (1.f / 256.f);
  float q = 0.f;
#pragma unroll
  for (int j = 0; j < 8; ++j) { float d = x[j] - mu; q += d * d; }
  float rs = rsqrtf(rsum32(q) * (1.f / 256.f) + EPSF);
  float o[8];
#pragma unroll
  for (int j = 0; j < 8; ++j) o[j] = (x[j] - mu) * rs * g[d0 + j] + b[d0 + j];
  uint4 w;
  w.x = bfpack2(o[0], o[1]); w.y = bfpack2(o[2], o[3]);
  w.z = bfpack2(o[4], o[5]); w.w = bfpack2(o[6], o[7]);
  *(uint4*)dst = w;
}

// ---------------- prep: wqk + bqk + weight conversion + zero pl/U buffers ----------
__global__ __launch_bounds__(256) void k_prep(
    const float* __restrict__ Wq, const float* __restrict__ Wk,
    const float* __restrict__ bq, unsigned short* __restrict__ Wqk_b,
    float* __restrict__ bqk, const float* __restrict__ Wv,
    const float* __restrict__ Wih, const float* __restrict__ Whh,
    const float* __restrict__ W1, const float* __restrict__ W2,
    const float* __restrict__ bih, const float* __restrict__ bhh,
    unsigned* Wv_b, unsigned* Wzr_b, unsigned* Win_b, unsigned* Whn_b,
    unsigned* W1_b, unsigned* W2_b, float* bzr, float* zbuf) {
  const int u = blockIdx.x, tid = threadIdx.x;
  if (u < 32) {  // Wqk_b[c][d] = bf16(sum_e Wq[e][d]*Wk[e][c]), 8 c per block
    const int c0 = u * 8;
    float acc[8] = {0.f, 0.f, 0.f, 0.f, 0.f, 0.f, 0.f, 0.f};
    for (int e = 0; e < 256; ++e) {
      float wq = Wq[e * 256 + tid];
      const float* wk = Wk + e * 256 + c0;
#pragma unroll
      for (int j = 0; j < 8; ++j) acc[j] += wq * wk[j];
    }
#pragma unroll
    for (int j = 0; j < 8; ++j) Wqk_b[(c0 + j) * 256 + tid] = bf16r(acc[j]);
  } else if (u == 32) {
    float acc = 0.f;
    for (int e = 0; e < 256; ++e) acc += bq[e] * Wk[e * 256 + tid];
    bqk[tid] = acc;
  } else if (u < 1185) {
    int p = (u - 33) * 256 + tid;  // bf16-pair index
    const float* src; unsigned* dst;
    if (p < 32768) { src = Wv + 2 * p; dst = Wv_b + p; }
    else if (p < 163840) {
      int q = p - 32768, row = q >> 8, col = (q & 255) * 2;
      src = (col < 256) ? (Wih + row * 256 + col) : (Whh + row * 256 + col - 256);
      dst = Wzr_b + q;
    }
    else if (p < 196608) { int q = p - 163840; src = Wih + 512 * 256 + 2 * q; dst = Win_b + q; }
    else if (p < 229376) { int q = p - 196608; src = Whh + 512 * 256 + 2 * q; dst = Whn_b + q; }
    else if (p < 262144) { int q = p - 229376; src = W1 + 2 * q; dst = W1_b + q; }
    else { int q = p - 262144; src = W2 + 2 * q; dst = W2_b + q; }
    dst[0] = bfpack2(src[0], src[1]);
  } else if (u < 1187) {
    int i = (u - 1185) * 256 + tid;
    if (i < 512) bzr[i] = bih[i] + bhh[i];
  } else {  // zero pl3 (3*512) + ua3 (3*131072) floats = 98688 float4
    int idx = (u - 1187) * 256 + tid;
    if (idx < 98688) ((float4*)zbuf)[idx] = make_float4(0.f, 0.f, 0.f, 0.f);
  }
}

// ---------------- slots = mu + sigma*noise; q8 = fp8(LN(slots)@WqkT + bqk) ----------
__global__ __launch_bounds__(512) void k_qk0(const float* __restrict__ noise,
                                             const float* __restrict__ s_mu,
                                             const float* __restrict__ s_sg,
                                             const float* __restrict__ gsl,
                                             const float* __restrict__ bsl,
                                             const unsigned short* __restrict__ Wqk_b,
                                             const float* __restrict__ bqk,
                                             float* __restrict__ slots,
                                             unsigned char* __restrict__ qk8) {
  __shared__ __align__(16) unsigned short lnb[16 * 264];
  const int tid = threadIdx.x, bb = blockIdx.x;
  const int lane = tid & 63, wave = tid >> 6;
  const int m16 = lane & 15, quad = lane >> 4;
  const int row = tid >> 5, l32 = tid & 31, d0 = l32 * 8;
  {
    const int grow = bb * 16 + row;            // = b*8 + s
    const int sidx = (grow & 7) * 256 + d0;
    const float* np = noise + (size_t)grow * 256 + d0;
    float4 n0 = *(const float4*)np, n1 = *(const float4*)(np + 4);
    float4 m0 = *(const float4*)(s_mu + sidx), m1 = *(const float4*)(s_mu + sidx + 4);
    float4 g0 = *(const float4*)(s_sg + sidx), g1 = *(const float4*)(s_sg + sidx + 4);
    float x[8] = {m0.x + g0.x * n0.x, m0.y + g0.y * n0.y,
                  m0.z + g0.z * n0.z, m0.w + g0.w * n0.w,
                  m1.x + g1.x * n1.x, m1.y + g1.y * n1.y,
                  m1.z + g1.z * n1.z, m1.w + g1.w * n1.w};
    float* sp_ = slots + (size_t)grow * 256 + d0;
    float4 o0, o1;
    o0.x = x[0]; o0.y = x[1]; o0.z = x[2]; o0.w = x[3];
    o1.x = x[4]; o1.y = x[5]; o1.z = x[6]; o1.w = x[7];
    *(float4*)sp_ = o0; *(float4*)(sp_ + 4) = o1;
    ln_row8(x, gsl, bsl, d0, lnb + row * 264 + d0);
  }
  __syncthreads();
  short8 a8[8];
  load_af<8>(a8, lnb, 264, m16, quad);
#pragma unroll
  for (int i = 0; i < 2; ++i) {
    int t = wave + 8 * i;
    f32x4 acc = gemm_tile<8>(a8, Wqk_b + (size_t)(t * 16 + m16) * 256 + quad * 8,
                             bqk[t * 16 + m16]);
#pragma unroll
    for (int r = 0; r < 4; ++r)
      qk8[(size_t)(bb * 16 + quad * 4 + r) * 256 + t * 16 + m16] =
          (unsigned char)f8q(acc[r]);
  }
}

// ---------------- kA: P = exp(q.x/16), no LDS, no barriers ----------------
// Block (c64, b) = 64 rows; wave w owns rows c64*64 + w*16 + (0..15).
// Lane(m16,quad): A-frag q8[s=m16][k=quad*8+j]; B-frag x[row=..+m16][same k].
// D: lane holds P[s=quad*4+r][n=m16-col]; s<8 stored to ppg, l-sums atomicAdd.
template <bool FIRST>
__global__ __launch_bounds__(256) void k_attnA(const float* __restrict__ xin,
                                               unsigned char* __restrict__ xbf,
                                               const unsigned char* __restrict__ q8,
                                               unsigned char* __restrict__ ppg,
                                               float* __restrict__ plf) {
  const int tid = threadIdx.x, lane = tid & 63, wave = tid >> 6;
  const int m16 = lane & 15, quad = lane >> 4;
  const int c64 = blockIdx.x, b = blockIdx.y;
  const size_t grow = (size_t)b * Nn + c64 * 64 + wave * 16 + m16;
  LL aq[8];
  {
    const unsigned char* qrow = q8 + ((size_t)b * 8 + (m16 & 7)) * 256 + quad * 8;
#pragma unroll
    for (int kk = 0; kk < 8; ++kk) {
      long long v = *(const long long*)(qrow + kk * 32);
      aq[kk].l = (m16 >= 8) ? 0ll : v;
    }
  }
  f32x4 pacc = (f32x4){0.f, 0.f, 0.f, 0.f};
  if (FIRST) {
    const float* xr = xin + grow * 256 + quad * 8;
    unsigned char* xw = xbf + grow * 256 + quad * 8;
#pragma unroll
    for (int kk = 0; kk < 8; ++kk) {
      float4 v0 = *(const float4*)(xr + kk * 32);
      float4 v1 = *(const float4*)(xr + kk * 32 + 4);
      LL bf;
      bf.u[0] = f8q(v0.x) | (f8q(v0.y) << 8) | (f8q(v0.z) << 16) | (f8q(v0.w) << 24);
      bf.u[1] = f8q(v1.x) | (f8q(v1.y) << 8) | (f8q(v1.z) << 16) | (f8q(v1.w) << 24);
      *(uint2*)(xw + kk * 32) = make_uint2(bf.u[0], bf.u[1]);
      pacc = __builtin_amdgcn_mfma_f32_16x16x32_fp8_fp8(aq[kk].l, bf.l, pacc, 0, 0, 0);
    }
  } else {
    const unsigned char* xr = xbf + grow * 256 + quad * 8;
#pragma unroll
    for (int kk = 0; kk < 8; ++kk) {
      LL bf;
      bf.l = *(const long long*)(xr + kk * 32);
      pacc = __builtin_amdgcn_mfma_f32_16x16x32_fp8_fp8(aq[kk].l, bf.l, pacc, 0, 0, 0);
    }
  }
  const int u = b * CH + (c64 >> 2);
  const int nloc = (c64 & 3) * 64 + wave * 16 + m16;
  float lacc[4];
#pragma unroll
  for (int r = 0; r < 4; ++r) {
    float p = __expf(pacc[r] * 0.0625f);
    lacc[r] = p;
    if (quad < 2)
      ppg[((size_t)u * 8 + quad * 4 + r) * 256 + nloc] = (unsigned char)f8q(p);
  }
#pragma unroll
  for (int r = 0; r < 4; ++r) {
    float v = lacc[r];
    v += __shfl_xor(v, 1); v += __shfl_xor(v, 2);
    v += __shfl_xor(v, 4); v += __shfl_xor(v, 8);
    if (m16 == 0 && quad < 2) atomicAdd(&plf[b * 8 + quad * 4 + r], v);
  }
}

// ---------------- kB: U += X^T @ P, transpose-only LDS, 1 barrier/chunk ----------
__global__ __launch_bounds__(256) void k_attnB(const unsigned char* __restrict__ xbf,
                                               const unsigned char* __restrict__ ppg,
                                               float* __restrict__ ua) {
  __shared__ __align__(16) unsigned xt[2][64 * 68];  // [d>>2][n] dwords
  const int tid = threadIdx.x, lane = tid & 63, wave = tid >> 6;
  const int m16 = lane & 15, quad = lane >> 4;
  const int c = blockIdx.x, b = blockIdx.y;
  const int u = b * CH + c;
  const size_t row0 = (size_t)b * Nn + (size_t)c * 256;
  const unsigned bsel = (m16 & 3) | (((m16 & 3) + 4) << 8);
  // hoist all 8 P fragments (ch 0..3 x nh 0..1) from global
  LL bp[8];
  {
    const unsigned char* bpp = ppg + (size_t)u * 2048 + (m16 & 7) * 256 + quad * 8;
#pragma unroll
    for (int k8 = 0; k8 < 8; ++k8) {
      long long v = *(const long long*)(bpp + k8 * 32);
      bp[k8].l = (m16 >= 8) ? 0ll : v;
    }
  }
  f32x4 acc[4];
#pragma unroll
  for (int t = 0; t < 4; ++t) acc[t] = (f32x4){0.f, 0.f, 0.f, 0.f};
  const uint4* xb4 = (const uint4*)(xbf + row0 * 256);
  uint4 pr[4];
#pragma unroll
  for (int i = 0; i < 4; ++i) pr[i] = xb4[i * 256 + tid];

  for (int ch = 0; ch < 4; ++ch) {
    unsigned* xtb = xt[ch & 1];
#pragma unroll
    for (int i = 0; i < 4; ++i) {
      int flat = i * 256 + tid, n = flat >> 4, od = flat & 15;
      xtb[(od * 4 + 0) * 68 + n] = pr[i].x;
      xtb[(od * 4 + 1) * 68 + n] = pr[i].y;
      xtb[(od * 4 + 2) * 68 + n] = pr[i].z;
      xtb[(od * 4 + 3) * 68 + n] = pr[i].w;
    }
    __syncthreads();
    if (ch + 1 < 4) {
#pragma unroll
      for (int i = 0; i < 4; ++i) pr[i] = xb4[(ch + 1) * 1024 + i * 256 + tid];
    }
#pragma unroll
    for (int nh = 0; nh < 2; ++nh) {
#pragma unroll
      for (int t = 0; t < 4; ++t) {
        int dq = wave * 16 + t * 4 + (m16 >> 2);
        const unsigned* xtp = xtb + dq * 68 + nh * 32 + quad * 8;
        uint4 w0 = *(const uint4*)xtp;
        uint4 w1 = *(const uint4*)(xtp + 4);
        unsigned e0 = __builtin_amdgcn_perm(w0.y, w0.x, bsel);
        unsigned e1 = __builtin_amdgcn_perm(w0.w, w0.z, bsel);
        unsigned e2 = __builtin_amdgcn_perm(w1.y, w1.x, bsel);
        unsigned e3 = __builtin_amdgcn_perm(w1.w, w1.z, bsel);
        LL af;
        af.u[0] = __builtin_amdgcn_perm(e1, e0, 0x05040100u);
        af.u[1] = __builtin_amdgcn_perm(e3, e2, 0x05040100u);
        acc[t] = __builtin_amdgcn_mfma_f32_16x16x32_fp8_fp8(af.l, bp[ch * 2 + nh].l,
                                                            acc[t], 0, 0, 0);
      }
    }
    // no trailing barrier: next chunk stages the other buffer; reuse of this one
    // (ch+2) is ordered by barrier(ch+1).
  }
  if (m16 < 8) {
    const int d0w = wave * 64;
#pragma unroll
    for (int t = 0; t < 4; ++t)
#pragma unroll
      for (int r = 0; r < 4; ++r)
        atomicAdd(&ua[((size_t)b * 8 + m16) * 256 + d0w + t * 16 + quad * 4 + r],
                  acc[t][r]);
  }
}

// ---------------- fused slot update: combine+Wv+GRU+MLP+LN+next-q8 ----------------
// 32 blocks x 512 threads; block = 16 rows (2 batches x 8 slots).
__global__ __launch_bounds__(512) void k_upd(
    const float* __restrict__ plf, const float* __restrict__ ua,
    const unsigned short* __restrict__ Wv_b, const float* __restrict__ bv,
    const unsigned short* __restrict__ Wzr_b, const float* __restrict__ bzr,
    const unsigned short* __restrict__ Win_b, const float* __restrict__ bin,
    const unsigned short* __restrict__ Whn_b, const float* __restrict__ bhn,
    const unsigned short* __restrict__ W1_b, const float* __restrict__ b1,
    const unsigned short* __restrict__ W2_b, const float* __restrict__ b2,
    const float* __restrict__ gml, const float* __restrict__ bml,
    const float* __restrict__ gsl, const float* __restrict__ bsl,
    const unsigned short* __restrict__ Wqk_b, const float* __restrict__ bqk,
    float* __restrict__ slots, unsigned char* __restrict__ qk8,
    float* __restrict__ dout) {
  __shared__ __align__(16) unsigned short cat[16 * 520];
  __shared__ __align__(16) float sp[16 * 260];
  __shared__ __align__(16) float s1[16 * 260];
  __shared__ __align__(16) unsigned short lnb[16 * 264];
  const int tid = threadIdx.x, bb = blockIdx.x;
  const int lane = tid & 63, wave = tid >> 6;
  const int m16 = lane & 15, quad = lane >> 4;
  const int row = tid >> 5, l32 = tid & 31, d0 = l32 * 8;
  const int bat = 2 * bb + (row >> 3), sl = row & 7;
  // ---- 1: u' = U/L -> cat bf16; h_prev -> sp f32 + cat bf16 ----
  {
    float li = 1.f / plf[bat * 8 + sl];
    const float* up = ua + ((size_t)(bat * 8 + sl)) * 256 + d0;
    float4 a0 = *(const float4*)up, a1 = *(const float4*)(up + 4);
    uint4 o;
    o.x = bfpack2(a0.x * li, a0.y * li); o.y = bfpack2(a0.z * li, a0.w * li);
    o.z = bfpack2(a1.x * li, a1.y * li); o.w = bfpack2(a1.z * li, a1.w * li);
    *(uint4*)(cat + row * 520 + d0) = o;
    const float* sp_ = slots + (size_t)(bb * 16 + row) * 256 + d0;
    float4 h0 = *(const float4*)sp_, h1 = *(const float4*)(sp_ + 4);
    *(float4*)(sp + row * 260 + d0) = h0;
    *(float4*)(sp + row * 260 + d0 + 4) = h1;
    uint4 hb;
    hb.x = bfpack2(h0.x, h0.y); hb.y = bfpack2(h0.z, h0.w);
    hb.z = bfpack2(h1.x, h1.y); hb.w = bfpack2(h1.z, h1.w);
    *(uint4*)(cat + row * 520 + 256 + d0) = hb;
  }
  __syncthreads();
  short8 afr[16];
  load_af<8>(afr, cat, 520, m16, quad);
  f32x4 accv[2];
#pragma unroll
  for (int i = 0; i < 2; ++i) {
    int t = wave + 8 * i;
    accv[i] = gemm_tile<8>(afr, Wv_b + (size_t)(t * 16 + m16) * 256 + quad * 8,
                           bv[t * 16 + m16]);
  }
  __syncthreads();
#pragma unroll
  for (int i = 0; i < 2; ++i) {
    int t = wave + 8 * i;
#pragma unroll
    for (int r = 0; r < 4; ++r)
      cat[(quad * 4 + r) * 520 + t * 16 + m16] = bf16r(accv[i][r]);
  }
  __syncthreads();
  load_af<16>(afr, cat, 520, m16, quad);
  f32x4 rr[2], zz[2];
#pragma unroll
  for (int i = 0; i < 2; ++i) {
    int t = wave + 8 * i;
    f32x4 ar = gemm_tile<16>(afr, Wzr_b + (size_t)(t * 16 + m16) * 512 + quad * 8,
                             bzr[t * 16 + m16]);
    f32x4 az = gemm_tile<16>(afr, Wzr_b + (size_t)((t + 16) * 16 + m16) * 512 + quad * 8,
                             bzr[(t + 16) * 16 + m16]);
#pragma unroll
    for (int r = 0; r < 4; ++r) { rr[i][r] = sigm(ar[r]); zz[i][r] = sigm(az[r]); }
  }
#pragma unroll
  for (int i = 0; i < 2; ++i) {
    int t = wave + 8 * i, col = t * 16 + m16;
    f32x4 ain = gemm_tile<8>(afr, Win_b + (size_t)(t * 16 + m16) * 256 + quad * 8,
                             bin[col]);
    f32x4 ahn = gemm_tile<8>(afr + 8, Whn_b + (size_t)(t * 16 + m16) * 256 + quad * 8,
                             bhn[col]);
#pragma unroll
    for (int r = 0; r < 4; ++r) {
      int rw = quad * 4 + r;
      float nin = ain[r] + rr[i][r] * ahn[r];
      float nn = 1.f - 2.f / (__expf(2.f * nin) + 1.f);  // tanh
      float hpc = sp[rw * 260 + col];
      s1[rw * 260 + col] = hpc + (1.f - zz[i][r]) * nn + zz[i][r] * hpc;
    }
  }
  __syncthreads();
  {
    const float* s1r = s1 + row * 260 + d0;
    float4 v0 = *(const float4*)s1r, v1 = *(const float4*)(s1r + 4);
    float x[8] = {v0.x, v0.y, v0.z, v0.w, v1.x, v1.y, v1.z, v1.w};
    ln_row8(x, gml, bml, d0, lnb + row * 264 + d0);
  }
  __syncthreads();
  load_af<8>(afr, lnb, 264, m16, quad);
#pragma unroll
  for (int i = 0; i < 2; ++i) {
    int t = wave + 8 * i;
    f32x4 acc = gemm_tile<8>(afr, W1_b + (size_t)(t * 16 + m16) * 256 + quad * 8,
                             b1[t * 16 + m16]);
#pragma unroll
    for (int r = 0; r < 4; ++r)
      cat[(quad * 4 + r) * 520 + t * 16 + m16] = bf16r(fmaxf(acc[r], 0.f));
  }
  __syncthreads();
  load_af<8>(afr, cat, 520, m16, quad);
#pragma unroll
  for (int i = 0; i < 2; ++i) {
    int t = wave + 8 * i;
    f32x4 acc = gemm_tile<8>(afr, W2_b + (size_t)(t * 16 + m16) * 256 + quad * 8,
                             b2[t * 16 + m16]);
#pragma unroll
    for (int r = 0; r < 4; ++r) {
      int rw = quad * 4 + r, col = t * 16 + m16;
      float v = acc[r] + s1[rw * 260 + col];
      size_t gi = (size_t)(bb * 16 + rw) * 256 + col;
      slots[gi] = v;
      if (dout) dout[gi] = v;
      sp[rw * 260 + col] = v;
    }
  }
  __syncthreads();
  {
    const float* spr = sp + row * 260 + d0;
    float4 v0 = *(const float4*)spr, v1 = *(const float4*)(spr + 4);
    float x[8] = {v0.x, v0.y, v0.z, v0.w, v1.x, v1.y, v1.z, v1.w};
    ln_row8(x, gsl, bsl, d0, lnb + row * 264 + d0);
  }
  __syncthreads();
  load_af<8>(afr, lnb, 264, m16, quad);
#pragma unroll
  for (int i = 0; i < 2; ++i) {
    int t = wave + 8 * i;
    f32x4 acc = gemm_tile<8>(afr, Wqk_b + (size_t)(t * 16 + m16) * 256 + quad * 8,
                             bqk[t * 16 + m16]);
#pragma unroll
    for (int r = 0; r < 4; ++r)
      qk8[(size_t)(bb * 16 + quad * 4 + r) * 256 + t * 16 + m16] =
          (unsigned char)f8q(acc[r]);
  }
}

// ---------------- launch ----------------
extern "C" void kernel_launch(void* const* d_in, const int* in_sizes, int n_in,
                              void* d_out, int out_size, void* d_ws, size_t ws_size,
                              hipStream_t stream) {
  const float* inputs = (const float*)d_in[0];
  const float* noise = (const float*)d_in[1];
  const float* s_mu = (const float*)d_in[2];
  const float* s_sg = (const float*)d_in[3];
  const float* Wq = (const float*)d_in[4];
  const float* bq = (const float*)d_in[5];
  const float* Wk = (const float*)d_in[6];
  // d_in[7] = bk: unused (softmax-invariant)
  const float* Wv = (const float*)d_in[8];
  const float* bv = (const float*)d_in[9];
  const float* Wih = (const float*)d_in[10];
  const float* bih = (const float*)d_in[11];
  const float* Whh = (const float*)d_in[12];
  const float* bhh = (const float*)d_in[13];
  const float* W1 = (const float*)d_in[14];
  const float* b1 = (const float*)d_in[15];
  const float* W2 = (const float*)d_in[16];
  const float* b2 = (const float*)d_in[17];
  const float* gsl = (const float*)d_in[18];
  const float* bsl = (const float*)d_in[19];
  const float* gml = (const float*)d_in[20];
  const float* bml = (const float*)d_in[21];
  float* out = (float*)d_out;

  char* wsb = (char*)d_ws;
  unsigned char* xbf = (unsigned char*)wsb;           // fp8 inputs: 64 MiB used
  unsigned char* q8 = (unsigned char*)(wsb + ((size_t)Bn * Nn * Dd * 2));
  unsigned char* ppg = q8 + (size_t)Bn * Ss * Dd;     // 2 MiB
  float* fp = (float*)(ppg + (size_t)Bn * CH * Ss * 256);
  float* slots = fp; fp += Bn * Ss * Dd;
  float* bqk = fp;   fp += Dd;
  float* bzr = fp;   fp += 512;
  float* zbuf = fp;                                   // pl3 + ua3 contiguous
  float* pl3 = fp;   fp += 3 * 512;
  float* ua3 = fp;   fp += 3 * Bn * Ss * Dd;
  unsigned short* wb = (unsigned short*)fp;
  unsigned short* Wv_b = wb;  wb += 65536;
  unsigned short* Wzr_b = wb; wb += 262144;
  unsigned short* Win_b = wb; wb += 65536;
  unsigned short* Whn_b = wb; wb += 65536;
  unsigned short* W1_b = wb;  wb += 65536;
  unsigned short* W2_b = wb;  wb += 65536;
  unsigned short* Wqk_b = wb; wb += 65536;
  (void)in_sizes; (void)n_in; (void)out_size; (void)ws_size;

  k_prep<<<dim3(1573), dim3(256), 0, stream>>>(
      Wq, Wk, bq, Wqk_b, bqk, Wv, Wih, Whh, W1, W2, bih, bhh, (unsigned*)Wv_b,
      (unsigned*)Wzr_b, (unsigned*)Win_b, (unsigned*)Whn_b, (unsigned*)W1_b,
      (unsigned*)W2_b, bzr, zbuf);
  k_qk0<<<dim3(32), dim3(512), 0, stream>>>(noise, s_mu, s_sg, gsl, bsl, Wqk_b, bqk,
                                            slots, q8);
  for (int it = 0; it < 3; ++it) {
    float* plf = pl3 + it * 512;
    float* ua = ua3 + (size_t)it * Bn * Ss * Dd;
    if (it == 0)
      k_attnA<true><<<dim3(64, 64), dim3(256), 0, stream>>>(inputs, xbf, q8, ppg, plf);
    else
      k_attnA<false><<<dim3(64, 64), dim3(256), 0, stream>>>(inputs, xbf, q8, ppg, plf);
    k_attnB<<<dim3(CH, Bn), dim3(256), 0, stream>>>(xbf, ppg, ua);
    k_upd<<<dim3(32), dim3(512), 0, stream>>>(
        plf, ua, Wv_b, bv, Wzr_b, bzr, Win_b, bih + 512, Whn_b, bhh + 512, W1_b, b1,
        W2_b, b2, gml, bml, gsl, bsl, Wqk_b, bqk, slots, q8, (it == 2) ? out : nullptr);
  }
}

// Round 10
// 723.996 us; speedup vs baseline: 1.4515x; 1.4515x over previous
//
#include <hip/hip_runtime.h>

// SlotAttention, algebraically restructured:
//   logits = (LN(slots) @ (Wq^T @ Wk)) . x / 16   (q.bk term dropped: softmax-invariant)
//   updates = softmax-weighted-avg(x) @ Wv^T + bv  (attn rows sum to 1)
// R5-R12: six attn structures all ~680 us timed; fp8 halving of bytes: -21 us only.
// R13 (shallow split + atomics): +372 us, REVERTED; but exposed kA counters:
//   VALU 19% / MFMA 0.4% / HBM 15% / occ 71% -> nothing saturated even with no
//   LDS/barriers. All latency-model estimates off 5-20x; throughput measurements
//   (fills 84% HBM, xconv 5.7 TB/s) match spec. The "attn ~95us/iter" claim rests
//   on the unverified R8 fixed-overhead model.
// R14: SELF-CALIBRATING round. R12 structure, attn body templated on REPS and run
//   TWICE per dispatch (identical recompute; pl/pu stores idempotent -> bit-equal
//   output). dur(REPS=2) - dur(REPS=1-baseline 678) = 3*T_attn, model-free; and
//   the doubled attn surfaces in top-5 with full counters. Rider (R13-verified):
//   q stored fp8 by qk0/upd; attn loads aq fragments directly (no per-thread f8q).

constexpr int Bn = 64;    // batch
constexpr int Nn = 4096;  // inputs per batch
constexpr int Dd = 256;   // feature dim (== IN_D)
constexpr int Ss = 8;     // slots
constexpr int CH = 16;    // N-chunks per batch for attention
constexpr float EPSF = 1e-5f;

#define DEV __device__ __forceinline__

using short8 = __attribute__((ext_vector_type(8))) short;
using f32x4 = __attribute__((ext_vector_type(4))) float;
union U8 { short8 s; uint4 u; };
union LL { unsigned u[2]; long long l; };

DEV unsigned bfpack2(float lo, float hi) {
  unsigned ul = __float_as_uint(lo), uh = __float_as_uint(hi);
  ul = (ul + 0x7FFFu + ((ul >> 16) & 1u)) >> 16;         // RNE to bf16
  uh = (uh + 0x7FFFu + ((uh >> 16) & 1u)) & 0xFFFF0000u;
  return ul | uh;
}
DEV unsigned short bf16r(float x) {
  unsigned u = __float_as_uint(x);
  u = (u + 0x7FFFu + ((u >> 16) & 1u)) >> 16;
  return (unsigned short)u;
}
// fp32 -> OCP e4m3fn, RNE, satfinite. bias 7, max 448, denorm step 2^-9.
DEV unsigned f8q(float x) {
  unsigned u = __float_as_uint(x), s = (u >> 24) & 0x80u;
  float a = __uint_as_float(u & 0x7FFFFFFFu);
  if (a >= 448.f) return s | 0x7Eu;
  if (a < 0.015625f) {
    int m = (int)rintf(a * 512.f);
    return s | (unsigned)m;
  }
  unsigned v = (u & 0x7FFFFFFFu) + 0x7FFFFu + ((u >> 20) & 1u);
  unsigned E = (v >> 23) - 120u;
  unsigned M = (v >> 20) & 7u;
  if (E > 15u) return s | 0x7Eu;
  unsigned r = (E << 3) | M;
  if (r > 0x7Eu) r = 0x7Eu;
  return s | r;
}
DEV float rsum32(float v) {  // sum within each 32-lane half of a wave
  v += __shfl_xor(v, 1); v += __shfl_xor(v, 2); v += __shfl_xor(v, 4);
  v += __shfl_xor(v, 8); v += __shfl_xor(v, 16);
  return v;
}
DEV float sigm(float x) { return 1.f / (1.f + __expf(-x)); }

// ---- bf16 MFMA tile helpers (k_upd/k_qk0 path) ----
template <int NK>
DEV void load_af(short8* a, const unsigned short* base, int lda, int m16, int quad) {
  const unsigned short* p = base + m16 * lda + quad * 8;
#pragma unroll
  for (int kk = 0; kk < NK; ++kk) a[kk] = *(const short8*)(p + kk * 32);
}
template <int NK>
DEV f32x4 gemm_tile(const short8* a, const unsigned short* wr, float binit) {
  f32x4 acc = {binit, binit, binit, binit};
#pragma unroll
  for (int kk = 0; kk < NK; ++kk) {
    short8 b = *(const short8*)(wr + kk * 32);
    acc = __builtin_amdgcn_mfma_f32_16x16x32_bf16(a[kk], b, acc, 0, 0, 0);
  }
  return acc;
}

// LayerNorm over one 256-row held 8-per-thread by 32 lanes; writes bf16 packed out.
DEV void ln_row8(const float* x, const float* g, const float* b, int d0,
                 unsigned short* dst) {
  float s = x[0] + x[1] + x[2] + x[3] + x[4] + x[5] + x[6] + x[7];
  float mu = rsum32(s) * (1.f / 256.f);
  float q = 0.f;
#pragma unroll
  for (int j = 0; j < 8; ++j) { float d = x[j] - mu; q += d * d; }
  float rs = rsqrtf(rsum32(q) * (1.f / 256.f) + EPSF);
  float o[8];
#pragma unroll
  for (int j = 0; j < 8; ++j) o[j] = (x[j] - mu) * rs * g[d0 + j] + b[d0 + j];
  uint4 w;
  w.x = bfpack2(o[0], o[1]); w.y = bfpack2(o[2], o[3]);
  w.z = bfpack2(o[4], o[5]); w.w = bfpack2(o[6], o[7]);
  *(uint4*)dst = w;
}

// ---------------- prep: wqk (8 cols/block) + bqk + weight conversion ----------------
__global__ __launch_bounds__(256) void k_prep(
    const float* __restrict__ Wq, const float* __restrict__ Wk,
    const float* __restrict__ bq, unsigned short* __restrict__ Wqk_b,
    float* __restrict__ bqk, const float* __restrict__ Wv,
    const float* __restrict__ Wih, const float* __restrict__ Whh,
    const float* __restrict__ W1, const float* __restrict__ W2,
    const float* __restrict__ bih, const float* __restrict__ bhh,
    unsigned* Wv_b, unsigned* Wzr_b, unsigned* Win_b, unsigned* Whn_b,
    unsigned* W1_b, unsigned* W2_b, float* bzr) {
  const int u = blockIdx.x, tid = threadIdx.x;
  if (u < 32) {  // Wqk_b[c][d] = bf16(sum_e Wq[e][d]*Wk[e][c]), 8 c per block
    const int c0 = u * 8;
    float acc[8] = {0.f, 0.f, 0.f, 0.f, 0.f, 0.f, 0.f, 0.f};
    for (int e = 0; e < 256; ++e) {
      float wq = Wq[e * 256 + tid];
      const float* wk = Wk + e * 256 + c0;
#pragma unroll
      for (int j = 0; j < 8; ++j) acc[j] += wq * wk[j];
    }
#pragma unroll
    for (int j = 0; j < 8; ++j) Wqk_b[(c0 + j) * 256 + tid] = bf16r(acc[j]);
  } else if (u == 32) {
    float acc = 0.f;
    for (int e = 0; e < 256; ++e) acc += bq[e] * Wk[e * 256 + tid];
    bqk[tid] = acc;
  } else {
    int cu = u - 33;
    if (cu >= 1152) {
      int i = (cu - 1152) * 256 + tid;
      if (i < 512) bzr[i] = bih[i] + bhh[i];
      return;
    }
    int p = cu * 256 + tid;  // bf16-pair index
    const float* src; unsigned* dst;
    if (p < 32768) { src = Wv + 2 * p; dst = Wv_b + p; }
    else if (p < 163840) {
      int q = p - 32768, row = q >> 8, col = (q & 255) * 2;
      src = (col < 256) ? (Wih + row * 256 + col) : (Whh + row * 256 + col - 256);
      dst = Wzr_b + q;
    }
    else if (p < 196608) { int q = p - 163840; src = Wih + 512 * 256 + 2 * q; dst = Win_b + q; }
    else if (p < 229376) { int q = p - 196608; src = Whh + 512 * 256 + 2 * q; dst = Whn_b + q; }
    else if (p < 262144) { int q = p - 229376; src = W1 + 2 * q; dst = W1_b + q; }
    else { int q = p - 262144; src = W2 + 2 * q; dst = W2_b + q; }
    dst[0] = bfpack2(src[0], src[1]);
  }
}

// ---------------- inputs -> fp8 xbf, pure coalesced stream ----------------
__global__ __launch_bounds__(256) void k_xconv(const float* __restrict__ xin,
                                               unsigned char* __restrict__ xbf) {
#pragma unroll
  for (int j = 0; j < 4; ++j) {
    int flat = blockIdx.x * 1024 + j * 256 + threadIdx.x;
    const float4* src = (const float4*)(xin + (size_t)flat * 8);
    float4 v0 = src[0], v1 = src[1];
    uint2 o;
    o.x = f8q(v0.x) | (f8q(v0.y) << 8) | (f8q(v0.z) << 16) | (f8q(v0.w) << 24);
    o.y = f8q(v1.x) | (f8q(v1.y) << 8) | (f8q(v1.z) << 16) | (f8q(v1.w) << 24);
    ((uint2*)xbf)[flat] = o;
  }
}

// ---------------- slots = mu + sigma*noise; q8 = fp8(LN(slots)@WqkT + bqk) ----------
__global__ __launch_bounds__(512) void k_qk0(const float* __restrict__ noise,
                                             const float* __restrict__ s_mu,
                                             const float* __restrict__ s_sg,
                                             const float* __restrict__ gsl,
                                             const float* __restrict__ bsl,
                                             const unsigned short* __restrict__ Wqk_b,
                                             const float* __restrict__ bqk,
                                             float* __restrict__ slots,
                                             unsigned char* __restrict__ qk8) {
  __shared__ __align__(16) unsigned short lnb[16 * 264];
  const int tid = threadIdx.x, bb = blockIdx.x;
  const int lane = tid & 63, wave = tid >> 6;
  const int m16 = lane & 15, quad = lane >> 4;
  const int row = tid >> 5, l32 = tid & 31, d0 = l32 * 8;
  {
    const int grow = bb * 16 + row;            // = b*8 + s
    const int sidx = (grow & 7) * 256 + d0;
    const float* np = noise + (size_t)grow * 256 + d0;
    float4 n0 = *(const float4*)np, n1 = *(const float4*)(np + 4);
    float4 m0 = *(const float4*)(s_mu + sidx), m1 = *(const float4*)(s_mu + sidx + 4);
    float4 g0 = *(const float4*)(s_sg + sidx), g1 = *(const float4*)(s_sg + sidx + 4);
    float x[8] = {m0.x + g0.x * n0.x, m0.y + g0.y * n0.y,
                  m0.z + g0.z * n0.z, m0.w + g0.w * n0.w,
                  m1.x + g1.x * n1.x, m1.y + g1.y * n1.y,
                  m1.z + g1.z * n1.z, m1.w + g1.w * n1.w};
    float* sp_ = slots + (size_t)grow * 256 + d0;
    float4 o0, o1;
    o0.x = x[0]; o0.y = x[1]; o0.z = x[2]; o0.w = x[3];
    o1.x = x[4]; o1.y = x[5]; o1.z = x[6]; o1.w = x[7];
    *(float4*)sp_ = o0; *(float4*)(sp_ + 4) = o1;
    ln_row8(x, gsl, bsl, d0, lnb + row * 264 + d0);
  }
  __syncthreads();
  short8 a8[8];
  load_af<8>(a8, lnb, 264, m16, quad);
#pragma unroll
  for (int i = 0; i < 2; ++i) {
    int t = wave + 8 * i;
    f32x4 acc = gemm_tile<8>(a8, Wqk_b + (size_t)(t * 16 + m16) * 256 + quad * 8,
                             bqk[t * 16 + m16]);
#pragma unroll
    for (int r = 0; r < 4; ++r)
      qk8[(size_t)(bb * 16 + quad * 4 + r) * 256 + t * 16 + m16] =
          (unsigned char)f8q(acc[r]);
  }
}

// ---------------- fp8 MFMA attention pass (R12 structure; REPS-instrumented) ------
// Per 64-row chunk (4/block): stage xr (row-major) + xt (byte-transposed) -> bar ->
// phase A (fp8 MFMA from xr rows; P fp8 into pp) -> bar -> phase B (A-frag via
// v_perm byte-extract from xt) -> bar. REPS>1 recomputes identically (idempotent
// stores) for model-free attribution of attn kernel time.
template <int REPS>
__global__ __launch_bounds__(256) void k_attn(const unsigned char* __restrict__ xbf,
                                              const unsigned char* __restrict__ q8,
                                              float* __restrict__ pl,
                                              float* __restrict__ pu) {
  __shared__ __align__(16) unsigned xr[64 * 68];        // row-major: [n][68 dwords]
  __shared__ __align__(16) unsigned xt[64 * 68];        // transposed: [d>>2][68]
  __shared__ __align__(16) unsigned char pp[16 * 72];   // P[s][n] bytes
  __shared__ __align__(16) float lred[4][16];
  const int tid = threadIdx.x;
  const int lane = tid & 63, wave = tid >> 6;
  const int m16 = lane & 15, quad = lane >> 4;
  const int c = blockIdx.x, b = blockIdx.y;
  const int pb = (b * CH + c) * 8;
  const size_t row0 = (size_t)b * Nn + (size_t)c * 256;

  // q A-frags straight from fp8 q8 (R13-verified layout)
  LL aq[8];
  {
    const unsigned char* qrow = q8 + ((size_t)b * 8 + (m16 & 7)) * 256 + quad * 8;
#pragma unroll
    for (int kk = 0; kk < 8; ++kk) {
      long long v = *(const long long*)(qrow + kk * 32);
      aq[kk].l = (m16 >= 8) ? 0ll : v;
    }
  }
  const int d0w = wave * 64;
  const uint4* xb4 = (const uint4*)xbf;  // 16 granules of 16B per 256B row

  for (int rep = 0; rep < REPS; ++rep) {
    float lacc[4] = {0.f, 0.f, 0.f, 0.f};
    f32x4 acc[4];
#pragma unroll
    for (int t = 0; t < 4; ++t) acc[t] = (f32x4){0.f, 0.f, 0.f, 0.f};
    uint4 pr[4];
#pragma unroll
    for (int i = 0; i < 4; ++i) {  // prologue: chunk 0
      int flat = i * 256 + tid, n = flat >> 4, od = flat & 15;
      pr[i] = xb4[(row0 + n) * 16 + od];
    }
    for (int ch = 0; ch < 4; ++ch) {
      // ---- stage pr -> xr (row-major) + xt (transposed) ----
#pragma unroll
      for (int i = 0; i < 4; ++i) {
        int flat = i * 256 + tid, n = flat >> 4, od = flat & 15;
        *(uint4*)(xr + n * 68 + od * 4) = pr[i];
        xt[(od * 4 + 0) * 68 + n] = pr[i].x;
        xt[(od * 4 + 1) * 68 + n] = pr[i].y;
        xt[(od * 4 + 2) * 68 + n] = pr[i].z;
        xt[(od * 4 + 3) * 68 + n] = pr[i].w;
      }
      __syncthreads();
      if (ch + 1 < 4) {  // prefetch next chunk (overlaps A+B)
        const size_t nb = row0 + (size_t)(ch + 1) * 64;
#pragma unroll
        for (int i = 0; i < 4; ++i) {
          int flat = i * 256 + tid, n = flat >> 4, od = flat & 15;
          pr[i] = xb4[(nb + n) * 16 + od];
        }
      }
      // ---- phase A: P = q @ X^T (wave w owns n-tile w); logits*0.0625, exp ----
      {
        const int nt = wave;
        f32x4 pacc = (f32x4){0.f, 0.f, 0.f, 0.f};
        const unsigned* xrr = xr + (nt * 16 + m16) * 68 + quad * 2;
#pragma unroll
        for (int kk = 0; kk < 8; ++kk) {
          LL bf;
          bf.l = *(const long long*)(xrr + kk * 8);
          pacc = __builtin_amdgcn_mfma_f32_16x16x32_fp8_fp8(aq[kk].l, bf.l, pacc, 0, 0, 0);
        }
        const int n = nt * 16 + m16;
#pragma unroll
        for (int r = 0; r < 4; ++r) {
          float p = __expf(pacc[r] * 0.0625f);  // |logit| small: no max-shift needed
          lacc[r] += p;
          pp[(quad * 4 + r) * 72 + n] = (unsigned char)f8q(p);
        }
      }
      __syncthreads();
      // ---- phase B: U^T += X^T @ P (wave owns 64 d-cols; 2 n-halves) ----
      const unsigned bsel = (m16 & 3) | (((m16 & 3) + 4) << 8);
#pragma unroll
      for (int nh = 0; nh < 2; ++nh) {
        LL bp;
        bp.l = *(const long long*)(pp + m16 * 72 + nh * 32 + quad * 8);
#pragma unroll
        for (int t = 0; t < 4; ++t) {
          int dq = (d0w + t * 16 + m16) >> 2;  // = wave*16 + t*4 + (m16>>2)
          const unsigned* xtp = xt + dq * 68 + nh * 32 + quad * 8;
          uint4 w0 = *(const uint4*)xtp;
          uint4 w1 = *(const uint4*)(xtp + 4);
          unsigned e0 = __builtin_amdgcn_perm(w0.y, w0.x, bsel);
          unsigned e1 = __builtin_amdgcn_perm(w0.w, w0.z, bsel);
          unsigned e2 = __builtin_amdgcn_perm(w1.y, w1.x, bsel);
          unsigned e3 = __builtin_amdgcn_perm(w1.w, w1.z, bsel);
          LL af;
          af.u[0] = __builtin_amdgcn_perm(e1, e0, 0x05040100u);
          af.u[1] = __builtin_amdgcn_perm(e3, e2, 0x05040100u);
          acc[t] = __builtin_amdgcn_mfma_f32_16x16x32_fp8_fp8(af.l, bp.l, acc[t], 0, 0, 0);
        }
      }
      __syncthreads();
    }
    if (m16 < 8) {
#pragma unroll
      for (int t = 0; t < 4; ++t)
#pragma unroll
        for (int r = 0; r < 4; ++r)
          pu[(size_t)(pb + m16) * 256 + d0w + t * 16 + quad * 4 + r] = acc[t][r];
    }
#pragma unroll
    for (int r = 0; r < 4; ++r) {
      float v = lacc[r];
      v += __shfl_xor(v, 1); v += __shfl_xor(v, 2);
      v += __shfl_xor(v, 4); v += __shfl_xor(v, 8);
      if (m16 == 0) lred[wave][quad * 4 + r] = v;
    }
    __syncthreads();
    if (tid < 8)
      pl[pb + tid] = lred[0][tid] + lred[1][tid] + lred[2][tid] + lred[3][tid];
    __syncthreads();  // rep boundary: lred/pl ordered before next rep's overwrite
  }
}

// ---------------- fused slot update: combine+Wv+GRU+MLP+LN+next-q8 ----------------
// 32 blocks x 512 threads; block = 16 rows (2 batches x 8 slots).
__global__ __launch_bounds__(512) void k_upd(
    const float* __restrict__ pl, const float* __restrict__ pu,
    const unsigned short* __restrict__ Wv_b, const float* __restrict__ bv,
    const unsigned short* __restrict__ Wzr_b, const float* __restrict__ bzr,
    const unsigned short* __restrict__ Win_b, const float* __restrict__ bin,
    const unsigned short* __restrict__ Whn_b, const float* __restrict__ bhn,
    const unsigned short* __restrict__ W1_b, const float* __restrict__ b1,
    const unsigned short* __restrict__ W2_b, const float* __restrict__ b2,
    const float* __restrict__ gml, const float* __restrict__ bml,
    const float* __restrict__ gsl, const float* __restrict__ bsl,
    const unsigned short* __restrict__ Wqk_b, const float* __restrict__ bqk,
    float* __restrict__ slots, unsigned char* __restrict__ qk8,
    float* __restrict__ dout) {
  __shared__ __align__(16) unsigned short cat[16 * 520];
  __shared__ __align__(16) float sp[16 * 260];
  __shared__ __align__(16) float s1[16 * 260];
  __shared__ __align__(16) unsigned short lnb[16 * 264];
  const int tid = threadIdx.x, bb = blockIdx.x;
  const int lane = tid & 63, wave = tid >> 6;
  const int m16 = lane & 15, quad = lane >> 4;
  const int row = tid >> 5, l32 = tid & 31, d0 = l32 * 8;
  const int bat = 2 * bb + (row >> 3), sl = row & 7;
  {
    float L = 0.f;
#pragma unroll
    for (int cc = 0; cc < 16; ++cc) L += pl[(bat * 16 + cc) * 8 + sl];
    float li = 1.f / L;
    float a[8] = {0.f, 0.f, 0.f, 0.f, 0.f, 0.f, 0.f, 0.f};
    for (int cc = 0; cc < 16; ++cc) {
      const float* pp_ = pu + ((size_t)(bat * 16 + cc) * 8 + sl) * 256 + d0;
      float4 v0 = *(const float4*)pp_, v1 = *(const float4*)(pp_ + 4);
      a[0] += v0.x; a[1] += v0.y; a[2] += v0.z; a[3] += v0.w;
      a[4] += v1.x; a[5] += v1.y; a[6] += v1.z; a[7] += v1.w;
    }
    uint4 o;
    o.x = bfpack2(a[0] * li, a[1] * li); o.y = bfpack2(a[2] * li, a[3] * li);
    o.z = bfpack2(a[4] * li, a[5] * li); o.w = bfpack2(a[6] * li, a[7] * li);
    *(uint4*)(cat + row * 520 + d0) = o;
    const float* sp_ = slots + (size_t)(bb * 16 + row) * 256 + d0;
    float4 h0 = *(const float4*)sp_, h1 = *(const float4*)(sp_ + 4);
    *(float4*)(sp + row * 260 + d0) = h0;
    *(float4*)(sp + row * 260 + d0 + 4) = h1;
    uint4 hb;
    hb.x = bfpack2(h0.x, h0.y); hb.y = bfpack2(h0.z, h0.w);
    hb.z = bfpack2(h1.x, h1.y); hb.w = bfpack2(h1.z, h1.w);
    *(uint4*)(cat + row * 520 + 256 + d0) = hb;
  }
  __syncthreads();
  short8 afr[16];
  load_af<8>(afr, cat, 520, m16, quad);
  f32x4 accv[2];
#pragma unroll
  for (int i = 0; i < 2; ++i) {
    int t = wave + 8 * i;
    accv[i] = gemm_tile<8>(afr, Wv_b + (size_t)(t * 16 + m16) * 256 + quad * 8,
                           bv[t * 16 + m16]);
  }
  __syncthreads();
#pragma unroll
  for (int i = 0; i < 2; ++i) {
    int t = wave + 8 * i;
#pragma unroll
    for (int r = 0; r < 4; ++r)
      cat[(quad * 4 + r) * 520 + t * 16 + m16] = bf16r(accv[i][r]);
  }
  __syncthreads();
  load_af<16>(afr, cat, 520, m16, quad);
  f32x4 rr[2], zz[2];
#pragma unroll
  for (int i = 0; i < 2; ++i) {
    int t = wave + 8 * i;
    f32x4 ar = gemm_tile<16>(afr, Wzr_b + (size_t)(t * 16 + m16) * 512 + quad * 8,
                             bzr[t * 16 + m16]);
    f32x4 az = gemm_tile<16>(afr, Wzr_b + (size_t)((t + 16) * 16 + m16) * 512 + quad * 8,
                             bzr[(t + 16) * 16 + m16]);
#pragma unroll
    for (int r = 0; r < 4; ++r) { rr[i][r] = sigm(ar[r]); zz[i][r] = sigm(az[r]); }
  }
#pragma unroll
  for (int i = 0; i < 2; ++i) {
    int t = wave + 8 * i, col = t * 16 + m16;
    f32x4 ain = gemm_tile<8>(afr, Win_b + (size_t)(t * 16 + m16) * 256 + quad * 8,
                             bin[col]);
    f32x4 ahn = gemm_tile<8>(afr + 8, Whn_b + (size_t)(t * 16 + m16) * 256 + quad * 8,
                             bhn[col]);
#pragma unroll
    for (int r = 0; r < 4; ++r) {
      int rw = quad * 4 + r;
      float nin = ain[r] + rr[i][r] * ahn[r];
      float nn = 1.f - 2.f / (__expf(2.f * nin) + 1.f);  // tanh
      float hpc = sp[rw * 260 + col];
      s1[rw * 260 + col] = hpc + (1.f - zz[i][r]) * nn + zz[i][r] * hpc;
    }
  }
  __syncthreads();
  {
    const float* s1r = s1 + row * 260 + d0;
    float4 v0 = *(const float4*)s1r, v1 = *(const float4*)(s1r + 4);
    float x[8] = {v0.x, v0.y, v0.z, v0.w, v1.x, v1.y, v1.z, v1.w};
    ln_row8(x, gml, bml, d0, lnb + row * 264 + d0);
  }
  __syncthreads();
  load_af<8>(afr, lnb, 264, m16, quad);
#pragma unroll
  for (int i = 0; i < 2; ++i) {
    int t = wave + 8 * i;
    f32x4 acc = gemm_tile<8>(afr, W1_b + (size_t)(t * 16 + m16) * 256 + quad * 8,
                             b1[t * 16 + m16]);
#pragma unroll
    for (int r = 0; r < 4; ++r)
      cat[(quad * 4 + r) * 520 + t * 16 + m16] = bf16r(fmaxf(acc[r], 0.f));
  }
  __syncthreads();
  load_af<8>(afr, cat, 520, m16, quad);
#pragma unroll
  for (int i = 0; i < 2; ++i) {
    int t = wave + 8 * i;
    f32x4 acc = gemm_tile<8>(afr, W2_b + (size_t)(t * 16 + m16) * 256 + quad * 8,
                             b2[t * 16 + m16]);
#pragma unroll
    for (int r = 0; r < 4; ++r) {
      int rw = quad * 4 + r, col = t * 16 + m16;
      float v = acc[r] + s1[rw * 260 + col];
      size_t gi = (size_t)(bb * 16 + rw) * 256 + col;
      slots[gi] = v;
      if (dout) dout[gi] = v;
      sp[rw * 260 + col] = v;
    }
  }
  __syncthreads();
  {
    const float* spr = sp + row * 260 + d0;
    float4 v0 = *(const float4*)spr, v1 = *(const float4*)(spr + 4);
    float x[8] = {v0.x, v0.y, v0.z, v0.w, v1.x, v1.y, v1.z, v1.w};
    ln_row8(x, gsl, bsl, d0, lnb + row * 264 + d0);
  }
  __syncthreads();
  load_af<8>(afr, lnb, 264, m16, quad);
#pragma unroll
  for (int i = 0; i < 2; ++i) {
    int t = wave + 8 * i;
    f32x4 acc = gemm_tile<8>(afr, Wqk_b + (size_t)(t * 16 + m16) * 256 + quad * 8,
                             bqk[t * 16 + m16]);
#pragma unroll
    for (int r = 0; r < 4; ++r)
      qk8[(size_t)(bb * 16 + quad * 4 + r) * 256 + t * 16 + m16] =
          (unsigned char)f8q(acc[r]);
  }
}

// ---------------- launch ----------------
extern "C" void kernel_launch(void* const* d_in, const int* in_sizes, int n_in,
                              void* d_out, int out_size, void* d_ws, size_t ws_size,
                              hipStream_t stream) {
  const float* inputs = (const float*)d_in[0];
  const float* noise = (const float*)d_in[1];
  const float* s_mu = (const float*)d_in[2];
  const float* s_sg = (const float*)d_in[3];
  const float* Wq = (const float*)d_in[4];
  const float* bq = (const float*)d_in[5];
  const float* Wk = (const float*)d_in[6];
  // d_in[7] = bk: unused (softmax-invariant)
  const float* Wv = (const float*)d_in[8];
  const float* bv = (const float*)d_in[9];
  const float* Wih = (const float*)d_in[10];
  const float* bih = (const float*)d_in[11];
  const float* Whh = (const float*)d_in[12];
  const float* bhh = (const float*)d_in[13];
  const float* W1 = (const float*)d_in[14];
  const float* b1 = (const float*)d_in[15];
  const float* W2 = (const float*)d_in[16];
  const float* b2 = (const float*)d_in[17];
  const float* gsl = (const float*)d_in[18];
  const float* bsl = (const float*)d_in[19];
  const float* gml = (const float*)d_in[20];
  const float* bml = (const float*)d_in[21];
  float* out = (float*)d_out;

  char* wsb = (char*)d_ws;
  unsigned char* xbf = (unsigned char*)wsb;  // fp8 inputs: 64 MiB used
  float* fp = (float*)(wsb + (size_t)Bn * Nn * Dd * 2);
  float* slots = fp; fp += Bn * Ss * Dd;
  unsigned char* q8 = (unsigned char*)fp; fp += Bn * Ss * Dd;  // fp8 q (over-alloc)
  float* bqk = fp;   fp += Dd;
  float* pl = fp;    fp += Bn * CH * Ss;
  float* pu = fp;    fp += Bn * CH * Ss * Dd;
  float* bzr = fp;   fp += 512;
  unsigned short* wb = (unsigned short*)fp;
  unsigned short* Wv_b = wb;  wb += 65536;
  unsigned short* Wzr_b = wb; wb += 262144;
  unsigned short* Win_b = wb; wb += 65536;
  unsigned short* Whn_b = wb; wb += 65536;
  unsigned short* W1_b = wb;  wb += 65536;
  unsigned short* W2_b = wb;  wb += 65536;
  unsigned short* Wqk_b = wb; wb += 65536;
  (void)in_sizes; (void)n_in; (void)out_size; (void)ws_size;

  k_xconv<<<dim3(8192), dim3(256), 0, stream>>>(inputs, xbf);
  k_prep<<<dim3(1187), dim3(256), 0, stream>>>(
      Wq, Wk, bq, Wqk_b, bqk, Wv, Wih, Whh, W1, W2, bih, bhh, (unsigned*)Wv_b,
      (unsigned*)Wzr_b, (unsigned*)Win_b, (unsigned*)Whn_b, (unsigned*)W1_b,
      (unsigned*)W2_b, bzr);
  k_qk0<<<dim3(32), dim3(512), 0, stream>>>(noise, s_mu, s_sg, gsl, bsl, Wqk_b, bqk,
                                            slots, q8);
  for (int it = 0; it < 3; ++it) {
    k_attn<2><<<dim3(CH, Bn), dim3(256), 0, stream>>>(xbf, q8, pl, pu);
    k_upd<<<dim3(32), dim3(512), 0, stream>>>(
        pl, pu, Wv_b, bv, Wzr_b, bzr, Win_b, bih + 512, Whn_b, bhh + 512, W1_b, b1,
        W2_b, b2, gml, bml, gsl, bsl, Wqk_b, bqk, slots, q8, (it == 2) ? out : nullptr);
  }
}